// Round 9
// baseline (1748.940 us; speedup 1.0000x reference)
//
#include <hip/hip_runtime.h>
#include <hip/hip_bf16.h>
#include <stdint.h>
#include <math.h>

#define H 32
#define LAGN 50

typedef float f32x4 __attribute__((ext_vector_type(4)));
typedef short bf16x8 __attribute__((ext_vector_type(8)));

__device__ __forceinline__ float rcp_(float x){ return __builtin_amdgcn_rcpf(x); }
__device__ __forceinline__ float sigmoidf_(float x){ return rcp_(1.0f + __expf(-x)); }
__device__ __forceinline__ float tanhf_(float x){ return 1.0f - 2.0f*rcp_(__expf(2.0f*x) + 1.0f); }

// packed f32x2 -> bf16x2 (RNE) via v_cvt_pk path
__device__ __forceinline__ unsigned pk_bf2(float f0, float f1){
  union { __hip_bfloat162 b; unsigned u; } cv;
  cv.b = __float22bfloat162_rn(make_float2(f0, f1));
  return cv.u;
}
// 8 floats (two f32x4) -> hi/lo bf16x8 (error-compensated split)
__device__ __forceinline__ void cvt8v(f32x4 a, f32x4 b, bf16x8& hi, bf16x8& lo){
  union U { bf16x8 v; unsigned d[4]; } Hu, Lu;
  #pragma unroll
  for (int p=0;p<2;p++){
    float f0=a[2*p], f1=a[2*p+1];
    unsigned uh = pk_bf2(f0,f1);
    float h0 = __uint_as_float(uh<<16);
    float h1 = __uint_as_float(uh & 0xffff0000u);
    Hu.d[p] = uh;  Lu.d[p] = pk_bf2(f0-h0, f1-h1);
    float g0=b[2*p], g1=b[2*p+1];
    unsigned ug = pk_bf2(g0,g1);
    float k0 = __uint_as_float(ug<<16);
    float k1 = __uint_as_float(ug & 0xffff0000u);
    Hu.d[2+p] = ug;  Lu.d[2+p] = pk_bf2(g0-k0, g1-k1);
  }
  hi = Hu.v; lo = Lu.v;
}

// ---------------- MFMA LSTM + time-attention + fc (round-7 structure) -------
// 4 waves x 16 nodes per block, per-wave private LDS slab, no barriers.
// launch_bounds(256,4): round 7 used 116 VGPR at hint=2 but sat at ~1.5
// resident waves/SIMD; hint=4 (cap 128 >= 116) asks allocator/runtime for
// 4/SIMD. Round 8's 2-tile ILP variant spilled (WRITE_SIZE +3.4MB) -> reverted.
__global__ __launch_bounds__(256, 4) void k_lstm(
    const float* __restrict__ yx,    // [N,50]
    const float* __restrict__ w_ih,  // [128]
    const float* __restrict__ w_hh,  // [128,32]
    const float* __restrict__ b_ih,  // [128]
    const float* __restrict__ b_hh,  // [128]
    const float* __restrict__ att_W, // [50,32]
    const float* __restrict__ fc_W,  // [32,32]
    const float* __restrict__ fc_b,  // [32]
    float* __restrict__ x1,          // [N,32] out
    int N)
{
  __shared__ float hs[4][16*36];     // per-wave slab [16 rows][36]
  const int wv = threadIdx.x >> 6;
  const int l  = threadIdx.x & 63;
  const int q  = l >> 4;
  const int cl = l & 15;
  const int nb = blockIdx.x*64 + wv*16;
  float* HS = hs[wv];

  // B fragments of w_hh (hi/lo bf16), in VGPRs for all 50 steps
  bf16x8 Bhi[8], Blo[8];
  #pragma unroll
  for (int T=0; T<8; ++T){
    const float* p = w_hh + (size_t)(16*T + cl)*H + 8*q;
    f32x4 w0 = *(const f32x4*)p;
    f32x4 w1 = *(const f32x4*)(p+4);
    cvt8v(w0, w1, Bhi[T], Blo[T]);
  }

  float wihv[8], bsv[8];
  #pragma unroll
  for (int T=0;T<8;T++){
    int colg = 16*T + cl;
    wihv[T] = w_ih[colg];
    bsv[T]  = b_ih[colg] + b_hh[colg];
  }

  for (int i=l; i<16*36; i+=64) HS[i] = 0.f;

  float cst[4][2], Sv[4][2], Zv[4];
  #pragma unroll
  for (int idx=0;idx<4;idx++){
    Zv[idx]=0.f; cst[idx][0]=0.f; cst[idx][1]=0.f; Sv[idx][0]=0.f; Sv[idx][1]=0.f;
  }

  const int rr = nb + 4*q;
  const float* yp0 = yx + (size_t)(rr+0<N?rr+0:N-1)*LAGN;
  const float* yp1 = yx + (size_t)(rr+1<N?rr+1:N-1)*LAGN;
  const float* yp2 = yx + (size_t)(rr+2<N?rr+2:N-1)*LAGN;
  const float* yp3 = yx + (size_t)(rr+3<N?rr+3:N-1)*LAGN;

  #pragma unroll 1
  for (int t=0;t<LAGN;t++){
    float xtv[4] = {yp0[t], yp1[t], yp2[t], yp3[t]};
    float at0 = att_W[t*H + cl];
    float at1 = att_W[t*H + cl + 16];

    f32x4 a0 = *(const f32x4*)&HS[36*cl + 8*q];
    f32x4 a1 = *(const f32x4*)&HS[36*cl + 8*q + 4];
    bf16x8 Ahi, Alo;
    cvt8v(a0, a1, Ahi, Alo);

    f32x4 C[8];
    #pragma unroll
    for (int T=0;T<8;T++){
      f32x4 z;
      #pragma unroll
      for (int idx=0;idx<4;idx++) z[idx] = __builtin_fmaf(xtv[idx], wihv[T], bsv[T]);
      z = __builtin_amdgcn_mfma_f32_16x16x32_bf16(Ahi, Blo[T], z, 0,0,0);
      z = __builtin_amdgcn_mfma_f32_16x16x32_bf16(Alo, Bhi[T], z, 0,0,0);
      z = __builtin_amdgcn_mfma_f32_16x16x32_bf16(Ahi, Bhi[T], z, 0,0,0);
      C[T] = z;
    }

    float stp[4], hv[4][2];
    #pragma unroll
    for (int idx=0; idx<4; ++idx){
      stp[idx] = 0.f;
      #pragma unroll
      for (int jh=0; jh<2; ++jh){
        float iv = sigmoidf_(C[jh][idx]);
        float fv = sigmoidf_(C[2+jh][idx]);
        float gv = tanhf_(C[4+jh][idx]);
        float ov = sigmoidf_(C[6+jh][idx]);
        float cn = fv*cst[idx][jh] + iv*gv;
        cst[idx][jh] = cn;
        float hh = ov*tanhf_(cn);
        hv[idx][jh] = hh;
        stp[idx] += hh * (jh ? at1 : at0);
        HS[36*(4*q+idx) + cl + 16*jh] = hh;
      }
    }

    #pragma unroll
    for (int mask=1; mask<16; mask<<=1){
      #pragma unroll
      for (int idx=0;idx<4;idx++)
        stp[idx] += __shfl_xor(stp[idx], mask);
    }

    #pragma unroll
    for (int idx=0;idx<4;idx++){
      float pex = __expf(stp[idx]);   // scores bounded -> no max shift needed
      Zv[idx] += pex;
      Sv[idx][0] += pex*hv[idx][0];
      Sv[idx][1] += pex*hv[idx][1];
    }
  }

  #pragma unroll
  for (int idx=0;idx<4;idx++){
    float iz = rcp_(Zv[idx]);
    HS[36*(4*q+idx) + cl]      = Sv[idx][0]*iz;
    HS[36*(4*q+idx) + cl + 16] = Sv[idx][1]*iz;
  }
  f32x4 p0 = *(const f32x4*)&HS[36*cl + 8*q];
  f32x4 p1 = *(const f32x4*)&HS[36*cl + 8*q + 4];
  bf16x8 Phi, Plo;
  cvt8v(p0, p1, Phi, Plo);

  #pragma unroll
  for (int T=0;T<2;T++){
    f32x4 w0, w1;
    #pragma unroll
    for (int i=0;i<4;i++){
      w0[i] = fc_W[(size_t)(8*q+i)*H + 16*T + cl];
      w1[i] = fc_W[(size_t)(8*q+4+i)*H + 16*T + cl];
    }
    bf16x8 Fhi, Flo;
    cvt8v(w0, w1, Fhi, Flo);
    float fcbv = fc_b[16*T + cl];
    f32x4 z = {fcbv, fcbv, fcbv, fcbv};
    z = __builtin_amdgcn_mfma_f32_16x16x32_bf16(Phi, Flo, z, 0,0,0);
    z = __builtin_amdgcn_mfma_f32_16x16x32_bf16(Plo, Fhi, z, 0,0,0);
    z = __builtin_amdgcn_mfma_f32_16x16x32_bf16(Phi, Fhi, z, 0,0,0);
    #pragma unroll
    for (int idx=0;idx<4;idx++){
      int r = nb + 4*q + idx;
      if (r < N) x1[(size_t)r*H + 16*T + cl] = fmaxf(z[idx], 0.f);
    }
  }
}

// ---------------- GCN: CSR build ---------------------------------------------
__global__ void k_deg_init(float* __restrict__ deg, int* __restrict__ cnt, int N){
  int i = blockIdx.x*blockDim.x + threadIdx.x;
  if (i < N){ deg[i] = 1.0f; cnt[i] = 0; }   // self-loop weight 1.0
}

__global__ void k_deg_cnt(const int* __restrict__ ei, const float* __restrict__ ew,
                          float* __restrict__ deg, int* __restrict__ cnt, int E){
  int e = blockIdx.x*blockDim.x + threadIdx.x;
  if (e < E){
    int d = ei[E+e];
    atomicAdd(&deg[d], ew[e]);
    atomicAdd(&cnt[d], 1);
  }
}

__global__ void k_dis(float* __restrict__ deg, int N){
  int i = blockIdx.x*blockDim.x + threadIdx.x;
  if (i < N) deg[i] = __frcp_rn(sqrtf(deg[i]));  // deg >= 1 always
}

// 3-phase parallel scan: block sums -> scan of sums -> per-block scan+offset
__global__ __launch_bounds__(256) void k_scan1(const int* __restrict__ cnt,
                                               int* __restrict__ bsum, int N){
  __shared__ int wsm[4];
  int b = blockIdx.x, t = threadIdx.x;
  int base = b*1024 + t*4;
  int s = 0;
  #pragma unroll
  for (int i=0;i<4;i++) if (base+i < N) s += cnt[base+i];
  #pragma unroll
  for (int off=1; off<64; off<<=1) s += __shfl_xor(s, off);
  if ((t&63) == 0) wsm[t>>6] = s;
  __syncthreads();
  if (t == 0) bsum[b] = wsm[0]+wsm[1]+wsm[2]+wsm[3];
}

__global__ __launch_bounds__(64) void k_scan2(int* __restrict__ bsum, int nb){
  int lane = threadIdx.x;
  int carry = 0;
  for (int base=0; base<nb; base+=64){
    int i = base + lane;
    int v = (i<nb) ? bsum[i] : 0;
    int s = v;
    #pragma unroll
    for (int off=1; off<64; off<<=1){ int tt=__shfl_up(s,off); if (lane>=off) s+=tt; }
    if (i<nb) bsum[i] = carry + s - v;
    carry += __shfl(s, 63);
  }
}

__global__ __launch_bounds__(256) void k_scan3(int* cp,       // cnt in, start out
                                               const int* __restrict__ bsum,
                                               int* __restrict__ rowptr, int N){
  __shared__ int wsm[4];
  int b = blockIdx.x, t = threadIdx.x, lane = t&63, w = t>>6;
  int base = b*1024 + t*4;
  int v[4];
  #pragma unroll
  for (int i=0;i<4;i++) v[i] = (base+i<N) ? cp[base+i] : 0;
  int tsum = v[0]+v[1]+v[2]+v[3];
  int s = tsum;
  #pragma unroll
  for (int off=1; off<64; off<<=1){ int tt=__shfl_up(s,off); if (lane>=off) s+=tt; }
  if (lane==63) wsm[w] = s;
  __syncthreads();
  int woff = 0;
  #pragma unroll
  for (int k=0;k<4;k++) if (k<w) woff += wsm[k];
  int e = bsum[b] + woff + (s - tsum);
  #pragma unroll
  for (int i=0;i<4;i++){
    if (base+i < N){ rowptr[base+i] = e; cp[base+i] = e; }
    if (base+i == N-1) rowptr[N] = e + v[i];
    e += v[i];
  }
}

// scatter edges into dst-grouped CSR slots, {src, norm} fused in one int2
__global__ void k_fill(const int* __restrict__ ei, const float* __restrict__ ew,
                       const float* __restrict__ dis, int* __restrict__ pos,
                       int2* __restrict__ cedge, int E){
  int e = blockIdx.x*blockDim.x + threadIdx.x;
  if (e < E){
    int s = ei[e], d = ei[E+e];
    int slot = atomicAdd(&pos[d], 1);
    cedge[slot] = make_int2(s, __float_as_int(dis[s]*ew[e]*dis[d]));
  }
}

// xw = x @ W ; out = (1/deg)*xw + b   (self-loop contribution folded in)
__global__ __launch_bounds__(256) void k_xw(
    const float* __restrict__ x, const float* __restrict__ W,
    const float* __restrict__ b, const float* __restrict__ dis,
    float* __restrict__ xw, float* __restrict__ out, int N)
{
  int n = blockIdx.x*blockDim.x + threadIdx.x;
  if (n >= N) return;
  float xv[H];
  const float4* xr = (const float4*)(x + (size_t)n*H);
  #pragma unroll
  for (int q=0;q<H/4;q++){
    float4 v = xr[q];
    xv[4*q+0]=v.x; xv[4*q+1]=v.y; xv[4*q+2]=v.z; xv[4*q+3]=v.w;
  }
  float d = dis[n];
  float sn = d*d;               // = 1/deg
  float* xwr = xw + (size_t)n*H;
  float* outr = out + (size_t)n*H;
  #pragma unroll
  for (int j=0;j<H;j++){
    float a = 0.f;
    #pragma unroll
    for (int k=0;k<H;k++) a += xv[k]*W[k*H+j];
    xwr[j]  = a;
    outr[j] = sn*a + b[j];
  }
}

// atomic-free gather: one wave per dst node; lane = channel x 2-edge pair.
// FINAL=0: out[n] += sum.  FINAL=1: fuse the last linear layer -- row never
// hits memory; compute relu(dot(row, lw[0:32]) + dot(node_x, lw[32:36]) + lb)
// and store the scalar.
template<int FINAL>
__global__ __launch_bounds__(256) void k_gather(
    const int* __restrict__ rowptr, const int2* __restrict__ cedge,
    const float* __restrict__ xw, float* __restrict__ base,
    const float* __restrict__ nx, const float* __restrict__ lw,
    const float* __restrict__ lb, float* __restrict__ out, int N)
{
  int wid = (int)((blockIdx.x*256u + threadIdx.x) >> 6);
  if (wid >= N) return;
  int lane = threadIdx.x & 63;
  int ch = lane & 31;
  int eh = lane >> 5;
  int start = rowptr[wid], end = rowptr[wid+1];
  float acc = 0.f;
  for (int j = start + eh; j < end; j += 2){
    int2 e = cedge[j];
    acc += __int_as_float(e.y) * xw[(size_t)e.x*H + ch];
  }
  acc += __shfl_xor(acc, 32);
  if (FINAL == 0){
    if (eh == 0){
      float* o = base + (size_t)wid*H + ch;
      *o += acc;
    }
  } else {
    // full row value on eh==0 lanes: base (self-loop+bias) + neighbor sum
    float v = base[(size_t)wid*H + ch] + acc;
    float s = v * lw[ch];                 // eh==1 lanes recompute same (same acc)
    #pragma unroll
    for (int mask=1; mask<32; mask<<=1) s += __shfl_xor(s, mask);
    if (lane == 0){
      const float* nr = nx + (size_t)wid*4;
      float a = s + lb[0];
      #pragma unroll
      for (int f=0; f<4; f++) a += nr[f]*lw[H+f];
      out[wid] = fmaxf(a, 0.f);
    }
  }
}

extern "C" void kernel_launch(void* const* d_in, const int* in_sizes, int n_in,
                              void* d_out, int out_size, void* d_ws, size_t ws_size,
                              hipStream_t stream) {
  const float* node_x   = (const float*)d_in[0];
  const float* node_yx  = (const float*)d_in[1];
  const int*   edge_idx = (const int*)  d_in[2];
  const float* edge_w   = (const float*)d_in[3];
  const float* w_ih     = (const float*)d_in[4];
  const float* w_hh     = (const float*)d_in[5];
  const float* b_ih     = (const float*)d_in[6];
  const float* b_hh     = (const float*)d_in[7];
  const float* att_W    = (const float*)d_in[8];
  const float* fc_W     = (const float*)d_in[9];
  const float* fc_b     = (const float*)d_in[10];
  const float* gcn1_W   = (const float*)d_in[11];
  const float* gcn1_b   = (const float*)d_in[12];
  const float* gcn2_W   = (const float*)d_in[13];
  const float* gcn2_b   = (const float*)d_in[14];
  const float* lin_W    = (const float*)d_in[15];
  const float* lin_b    = (const float*)d_in[16];
  float* out = (float*)d_out;

  int N = in_sizes[0] / 4;     // node_x is [N,4]
  int E = in_sizes[3];         // edge_weight is [E]

  float* ws = (float*)d_ws;
  float* x1     = ws;                        // [N*32]
  float* xw     = x1  + (size_t)N*H;         // [N*32]
  float* o1     = xw  + (size_t)N*H;         // [N*32]
  float* deg    = o1  + (size_t)N*H;         // [N] (becomes dis)
  int*   rowptr = (int*)(deg + N);           // [N+1]
  int*   pos    = rowptr + (N+1);            // [N] (cnt -> start)
  uintptr_t ca  = ((uintptr_t)(pos + N) + 7) & ~(uintptr_t)7;
  int2*  cedge  = (int2*)ca;                 // [E] {src, norm}
  int*   bsum   = (int*)(cedge + E);         // [ceil(N/1024)]

  dim3 blk(256);
  int gN  = (N + 255) / 256;
  int gE  = (E + 255) / 256;
  int gL  = (N + 63) / 64;                   // 64 nodes per 256-thread block
  int gG  = (N + 3) / 4;                     // one wave per node
  int gS  = (N + 1023) / 1024;               // scan blocks

  // 1. LSTM + attention + fc (MFMA, round-7 structure, waves-per-eu hint 4)
  k_lstm<<<gL, blk, 0, stream>>>(node_yx, w_ih, w_hh, b_ih, b_hh,
                                 att_W, fc_W, fc_b, x1, N);
  // 2. CSR build: deg/count -> dis -> 3-phase scan -> fill
  k_deg_init<<<gN, blk, 0, stream>>>(deg, pos, N);
  k_deg_cnt <<<gE, blk, 0, stream>>>(edge_idx, edge_w, deg, pos, E);
  k_dis     <<<gN, blk, 0, stream>>>(deg, N);
  k_scan1   <<<gS, blk, 0, stream>>>(pos, bsum, N);
  k_scan2   <<<1, dim3(64), 0, stream>>>(bsum, gS);
  k_scan3   <<<gS, blk, 0, stream>>>(pos, bsum, rowptr, N);
  k_fill    <<<gE, blk, 0, stream>>>(edge_idx, edge_w, deg, pos, cedge, E);
  // 3. GCN layer 1: x1 -> (xw) -> o1
  k_xw       <<<gN, blk, 0, stream>>>(x1, gcn1_W, gcn1_b, deg, xw, o1, N);
  k_gather<0><<<gG, blk, 0, stream>>>(rowptr, cedge, xw, o1,
                                      nullptr, nullptr, nullptr, nullptr, N);
  // 4. GCN layer 2 + fused final linear: o1 -> (xw, x1 base) -> out
  k_xw       <<<gN, blk, 0, stream>>>(o1, gcn2_W, gcn2_b, deg, xw, x1, N);
  k_gather<1><<<gG, blk, 0, stream>>>(rowptr, cedge, xw, x1,
                                      node_x, lin_W, lin_b, out, N);
}

// Round 10
// 801.405 us; speedup vs baseline: 2.1823x; 2.1823x over previous
//
#include <hip/hip_runtime.h>
#include <hip/hip_bf16.h>
#include <stdint.h>
#include <math.h>

#define H 32
#define LAGN 50

typedef float f32x4 __attribute__((ext_vector_type(4)));
typedef short bf16x8 __attribute__((ext_vector_type(8)));

__device__ __forceinline__ float rcp_(float x){ return __builtin_amdgcn_rcpf(x); }
__device__ __forceinline__ float sigmoidf_(float x){ return rcp_(1.0f + __expf(-x)); }
__device__ __forceinline__ float tanhf_(float x){ return 1.0f - 2.0f*rcp_(__expf(2.0f*x) + 1.0f); }

// packed f32x2 -> bf16x2 (RNE) via v_cvt_pk path
__device__ __forceinline__ unsigned pk_bf2(float f0, float f1){
  union { __hip_bfloat162 b; unsigned u; } cv;
  cv.b = __float22bfloat162_rn(make_float2(f0, f1));
  return cv.u;
}
// 8 floats (two f32x4) -> hi/lo bf16x8 (error-compensated split)
__device__ __forceinline__ void cvt8v(f32x4 a, f32x4 b, bf16x8& hi, bf16x8& lo){
  union U { bf16x8 v; unsigned d[4]; } Hu, Lu;
  #pragma unroll
  for (int p=0;p<2;p++){
    float f0=a[2*p], f1=a[2*p+1];
    unsigned uh = pk_bf2(f0,f1);
    float h0 = __uint_as_float(uh<<16);
    float h1 = __uint_as_float(uh & 0xffff0000u);
    Hu.d[p] = uh;  Lu.d[p] = pk_bf2(f0-h0, f1-h1);
    float g0=b[2*p], g1=b[2*p+1];
    unsigned ug = pk_bf2(g0,g1);
    float k0 = __uint_as_float(ug<<16);
    float k1 = __uint_as_float(ug & 0xffff0000u);
    Hu.d[2+p] = ug;  Lu.d[2+p] = pk_bf2(g0-k0, g1-k1);
  }
  hi = Hu.v; lo = Lu.v;
}

// ---------------- MFMA LSTM + time-attention + fc (round-7 config, reverted) -
// 4 waves x 16 nodes per block, per-wave private LDS slab, no barriers.
// launch_bounds(256,2): the ~116-VGPR working set is incompressible --
// hint=4 (r9) forced VGPR=64 and spilled the weight fragments (4 GB scratch
// reads, 2.4x regression); 2-tile ILP (r8) also spilled. This config is the
// measured sweet spot (355us).
__global__ __launch_bounds__(256, 2) void k_lstm(
    const float* __restrict__ yx,    // [N,50]
    const float* __restrict__ w_ih,  // [128]
    const float* __restrict__ w_hh,  // [128,32]
    const float* __restrict__ b_ih,  // [128]
    const float* __restrict__ b_hh,  // [128]
    const float* __restrict__ att_W, // [50,32]
    const float* __restrict__ fc_W,  // [32,32]
    const float* __restrict__ fc_b,  // [32]
    float* __restrict__ x1,          // [N,32] out
    int N)
{
  __shared__ float hs[4][16*36];     // per-wave slab [16 rows][36]
  const int wv = threadIdx.x >> 6;
  const int l  = threadIdx.x & 63;
  const int q  = l >> 4;
  const int cl = l & 15;
  const int nb = blockIdx.x*64 + wv*16;
  float* HS = hs[wv];

  // B fragments of w_hh (hi/lo bf16), in VGPRs for all 50 steps
  bf16x8 Bhi[8], Blo[8];
  #pragma unroll
  for (int T=0; T<8; ++T){
    const float* p = w_hh + (size_t)(16*T + cl)*H + 8*q;
    f32x4 w0 = *(const f32x4*)p;
    f32x4 w1 = *(const f32x4*)(p+4);
    cvt8v(w0, w1, Bhi[T], Blo[T]);
  }

  float wihv[8], bsv[8];
  #pragma unroll
  for (int T=0;T<8;T++){
    int colg = 16*T + cl;
    wihv[T] = w_ih[colg];
    bsv[T]  = b_ih[colg] + b_hh[colg];
  }

  float cst[4][2], Sv[4][2], Zv[4];
  #pragma unroll
  for (int idx=0;idx<4;idx++){
    Zv[idx]=0.f; cst[idx][0]=0.f; cst[idx][1]=0.f; Sv[idx][0]=0.f; Sv[idx][1]=0.f;
  }

  const int rr = nb + 4*q;
  const float* yp0 = yx + (size_t)(rr+0<N?rr+0:N-1)*LAGN;
  const float* yp1 = yx + (size_t)(rr+1<N?rr+1:N-1)*LAGN;
  const float* yp2 = yx + (size_t)(rr+2<N?rr+2:N-1)*LAGN;
  const float* yp3 = yx + (size_t)(rr+3<N?rr+3:N-1)*LAGN;

  // t loop with t=0 peeled: h==0 at t=0, so C = b + x*w_ih directly
  // (no LDS read, no cvt, no MFMA on a zero matrix).
  #pragma unroll 1
  for (int t=0;t<LAGN;t++){
    float xtv[4] = {yp0[t], yp1[t], yp2[t], yp3[t]};
    float at0 = att_W[t*H + cl];
    float at1 = att_W[t*H + cl + 16];

    f32x4 C[8];
    if (t == 0){
      #pragma unroll
      for (int T=0;T<8;T++){
        #pragma unroll
        for (int idx=0;idx<4;idx++)
          C[T][idx] = __builtin_fmaf(xtv[idx], wihv[T], bsv[T]);
      }
    } else {
      f32x4 a0 = *(const f32x4*)&HS[36*cl + 8*q];
      f32x4 a1 = *(const f32x4*)&HS[36*cl + 8*q + 4];
      bf16x8 Ahi, Alo;
      cvt8v(a0, a1, Ahi, Alo);
      #pragma unroll
      for (int T=0;T<8;T++){
        f32x4 z;
        #pragma unroll
        for (int idx=0;idx<4;idx++) z[idx] = __builtin_fmaf(xtv[idx], wihv[T], bsv[T]);
        z = __builtin_amdgcn_mfma_f32_16x16x32_bf16(Ahi, Blo[T], z, 0,0,0);
        z = __builtin_amdgcn_mfma_f32_16x16x32_bf16(Alo, Bhi[T], z, 0,0,0);
        z = __builtin_amdgcn_mfma_f32_16x16x32_bf16(Ahi, Bhi[T], z, 0,0,0);
        C[T] = z;
      }
    }

    float stp[4], hv[4][2];
    #pragma unroll
    for (int idx=0; idx<4; ++idx){
      stp[idx] = 0.f;
      #pragma unroll
      for (int jh=0; jh<2; ++jh){
        float iv = sigmoidf_(C[jh][idx]);
        float fv = sigmoidf_(C[2+jh][idx]);
        float gv = tanhf_(C[4+jh][idx]);
        float ov = sigmoidf_(C[6+jh][idx]);
        float cn = fv*cst[idx][jh] + iv*gv;
        cst[idx][jh] = cn;
        float hh = ov*tanhf_(cn);
        hv[idx][jh] = hh;
        stp[idx] += hh * (jh ? at1 : at0);
        HS[36*(4*q+idx) + cl + 16*jh] = hh;
      }
    }

    #pragma unroll
    for (int mask=1; mask<16; mask<<=1){
      #pragma unroll
      for (int idx=0;idx<4;idx++)
        stp[idx] += __shfl_xor(stp[idx], mask);
    }

    #pragma unroll
    for (int idx=0;idx<4;idx++){
      float pex = __expf(stp[idx]);   // scores bounded -> no max shift needed
      Zv[idx] += pex;
      Sv[idx][0] += pex*hv[idx][0];
      Sv[idx][1] += pex*hv[idx][1];
    }
  }

  #pragma unroll
  for (int idx=0;idx<4;idx++){
    float iz = rcp_(Zv[idx]);
    HS[36*(4*q+idx) + cl]      = Sv[idx][0]*iz;
    HS[36*(4*q+idx) + cl + 16] = Sv[idx][1]*iz;
  }
  f32x4 p0 = *(const f32x4*)&HS[36*cl + 8*q];
  f32x4 p1 = *(const f32x4*)&HS[36*cl + 8*q + 4];
  bf16x8 Phi, Plo;
  cvt8v(p0, p1, Phi, Plo);

  #pragma unroll
  for (int T=0;T<2;T++){
    f32x4 w0, w1;
    #pragma unroll
    for (int i=0;i<4;i++){
      w0[i] = fc_W[(size_t)(8*q+i)*H + 16*T + cl];
      w1[i] = fc_W[(size_t)(8*q+4+i)*H + 16*T + cl];
    }
    bf16x8 Fhi, Flo;
    cvt8v(w0, w1, Fhi, Flo);
    float fcbv = fc_b[16*T + cl];
    f32x4 z = {fcbv, fcbv, fcbv, fcbv};
    z = __builtin_amdgcn_mfma_f32_16x16x32_bf16(Phi, Flo, z, 0,0,0);
    z = __builtin_amdgcn_mfma_f32_16x16x32_bf16(Plo, Fhi, z, 0,0,0);
    z = __builtin_amdgcn_mfma_f32_16x16x32_bf16(Phi, Fhi, z, 0,0,0);
    #pragma unroll
    for (int idx=0;idx<4;idx++){
      int r = nb + 4*q + idx;
      if (r < N) x1[(size_t)r*H + 16*T + cl] = fmaxf(z[idx], 0.f);
    }
  }
}

// ---------------- GCN: CSR build ---------------------------------------------
__global__ void k_deg_init(float* __restrict__ deg, int* __restrict__ cnt, int N){
  int i = blockIdx.x*blockDim.x + threadIdx.x;
  if (i < N){ deg[i] = 1.0f; cnt[i] = 0; }   // self-loop weight 1.0
}

__global__ void k_deg_cnt(const int* __restrict__ ei, const float* __restrict__ ew,
                          float* __restrict__ deg, int* __restrict__ cnt, int E){
  int e = blockIdx.x*blockDim.x + threadIdx.x;
  if (e < E){
    int d = ei[E+e];
    atomicAdd(&deg[d], ew[e]);
    atomicAdd(&cnt[d], 1);
  }
}

// 3-phase parallel scan; phase 1 also converts deg -> dis = deg^-1/2 in place
__global__ __launch_bounds__(256) void k_scan1(const int* __restrict__ cnt,
                                               int* __restrict__ bsum,
                                               float* __restrict__ deg, int N){
  __shared__ int wsm[4];
  int b = blockIdx.x, t = threadIdx.x;
  int base = b*1024 + t*4;
  int s = 0;
  #pragma unroll
  for (int i=0;i<4;i++) if (base+i < N){
    s += cnt[base+i];
    deg[base+i] = __frcp_rn(sqrtf(deg[base+i]));   // deg >= 1 always
  }
  #pragma unroll
  for (int off=1; off<64; off<<=1) s += __shfl_xor(s, off);
  if ((t&63) == 0) wsm[t>>6] = s;
  __syncthreads();
  if (t == 0) bsum[b] = wsm[0]+wsm[1]+wsm[2]+wsm[3];
}

__global__ __launch_bounds__(64) void k_scan2(int* __restrict__ bsum, int nb){
  int lane = threadIdx.x;
  int carry = 0;
  for (int base=0; base<nb; base+=64){
    int i = base + lane;
    int v = (i<nb) ? bsum[i] : 0;
    int s = v;
    #pragma unroll
    for (int off=1; off<64; off<<=1){ int tt=__shfl_up(s,off); if (lane>=off) s+=tt; }
    if (i<nb) bsum[i] = carry + s - v;
    carry += __shfl(s, 63);
  }
}

__global__ __launch_bounds__(256) void k_scan3(int* cp,       // cnt in, start out
                                               const int* __restrict__ bsum,
                                               int* __restrict__ rowptr, int N){
  __shared__ int wsm[4];
  int b = blockIdx.x, t = threadIdx.x, lane = t&63, w = t>>6;
  int base = b*1024 + t*4;
  int v[4];
  #pragma unroll
  for (int i=0;i<4;i++) v[i] = (base+i<N) ? cp[base+i] : 0;
  int tsum = v[0]+v[1]+v[2]+v[3];
  int s = tsum;
  #pragma unroll
  for (int off=1; off<64; off<<=1){ int tt=__shfl_up(s,off); if (lane>=off) s+=tt; }
  if (lane==63) wsm[w] = s;
  __syncthreads();
  int woff = 0;
  #pragma unroll
  for (int k=0;k<4;k++) if (k<w) woff += wsm[k];
  int e = bsum[b] + woff + (s - tsum);
  #pragma unroll
  for (int i=0;i<4;i++){
    if (base+i < N){ rowptr[base+i] = e; cp[base+i] = e; }
    if (base+i == N-1) rowptr[N] = e + v[i];
    e += v[i];
  }
}

// scatter edges into dst-grouped CSR slots, {src, norm} fused in one int2
__global__ void k_fill(const int* __restrict__ ei, const float* __restrict__ ew,
                       const float* __restrict__ dis, int* __restrict__ pos,
                       int2* __restrict__ cedge, int E){
  int e = blockIdx.x*blockDim.x + threadIdx.x;
  if (e < E){
    int s = ei[e], d = ei[E+e];
    int slot = atomicAdd(&pos[d], 1);
    cedge[slot] = make_int2(s, __float_as_int(dis[s]*ew[e]*dis[d]));
  }
}

// xw = x @ W ; out = (1/deg)*xw + b   (self-loop contribution folded in)
__global__ __launch_bounds__(256) void k_xw(
    const float* __restrict__ x, const float* __restrict__ W,
    const float* __restrict__ b, const float* __restrict__ dis,
    float* __restrict__ xw, float* __restrict__ out, int N)
{
  int n = blockIdx.x*blockDim.x + threadIdx.x;
  if (n >= N) return;
  float xv[H];
  const float4* xr = (const float4*)(x + (size_t)n*H);
  #pragma unroll
  for (int q=0;q<H/4;q++){
    float4 v = xr[q];
    xv[4*q+0]=v.x; xv[4*q+1]=v.y; xv[4*q+2]=v.z; xv[4*q+3]=v.w;
  }
  float d = dis[n];
  float sn = d*d;               // = 1/deg
  float* xwr = xw + (size_t)n*H;
  float* outr = out + (size_t)n*H;
  #pragma unroll
  for (int j=0;j<H;j++){
    float a = 0.f;
    #pragma unroll
    for (int k=0;k<H;k++) a += xv[k]*W[k*H+j];
    xwr[j]  = a;
    outr[j] = sn*a + b[j];
  }
}

// atomic-free gather: one wave per dst node; lane = channel x 2-edge pair.
// FINAL=0: base[n] += sum.  FINAL=1: fuse the last linear layer -- row never
// hits memory; out[n] = relu(dot(row, lw[0:32]) + dot(node_x, lw[32:36]) + lb).
template<int FINAL>
__global__ __launch_bounds__(256) void k_gather(
    const int* __restrict__ rowptr, const int2* __restrict__ cedge,
    const float* __restrict__ xw, float* __restrict__ base,
    const float* __restrict__ nx, const float* __restrict__ lw,
    const float* __restrict__ lb, float* __restrict__ out, int N)
{
  int wid = (int)((blockIdx.x*256u + threadIdx.x) >> 6);
  if (wid >= N) return;
  int lane = threadIdx.x & 63;
  int ch = lane & 31;
  int eh = lane >> 5;
  int start = rowptr[wid], end = rowptr[wid+1];
  float acc = 0.f;
  for (int j = start + eh; j < end; j += 2){
    int2 e = cedge[j];
    acc += __int_as_float(e.y) * xw[(size_t)e.x*H + ch];
  }
  acc += __shfl_xor(acc, 32);
  if (FINAL == 0){
    if (eh == 0){
      float* o = base + (size_t)wid*H + ch;
      *o += acc;
    }
  } else {
    float v = base[(size_t)wid*H + ch] + acc;   // both eh halves identical
    float s = v * lw[ch];
    #pragma unroll
    for (int mask=1; mask<32; mask<<=1) s += __shfl_xor(s, mask);
    if (lane == 0){
      const float* nr = nx + (size_t)wid*4;
      float a = s + lb[0];
      #pragma unroll
      for (int f=0; f<4; f++) a += nr[f]*lw[H+f];
      out[wid] = fmaxf(a, 0.f);
    }
  }
}

extern "C" void kernel_launch(void* const* d_in, const int* in_sizes, int n_in,
                              void* d_out, int out_size, void* d_ws, size_t ws_size,
                              hipStream_t stream) {
  const float* node_x   = (const float*)d_in[0];
  const float* node_yx  = (const float*)d_in[1];
  const int*   edge_idx = (const int*)  d_in[2];
  const float* edge_w   = (const float*)d_in[3];
  const float* w_ih     = (const float*)d_in[4];
  const float* w_hh     = (const float*)d_in[5];
  const float* b_ih     = (const float*)d_in[6];
  const float* b_hh     = (const float*)d_in[7];
  const float* att_W    = (const float*)d_in[8];
  const float* fc_W     = (const float*)d_in[9];
  const float* fc_b     = (const float*)d_in[10];
  const float* gcn1_W   = (const float*)d_in[11];
  const float* gcn1_b   = (const float*)d_in[12];
  const float* gcn2_W   = (const float*)d_in[13];
  const float* gcn2_b   = (const float*)d_in[14];
  const float* lin_W    = (const float*)d_in[15];
  const float* lin_b    = (const float*)d_in[16];
  float* out = (float*)d_out;

  int N = in_sizes[0] / 4;     // node_x is [N,4]
  int E = in_sizes[3];         // edge_weight is [E]

  float* ws = (float*)d_ws;
  float* x1     = ws;                        // [N*32]
  float* xw     = x1  + (size_t)N*H;         // [N*32]
  float* o1     = xw  + (size_t)N*H;         // [N*32]
  float* deg    = o1  + (size_t)N*H;         // [N] (becomes dis)
  int*   rowptr = (int*)(deg + N);           // [N+1]
  int*   pos    = rowptr + (N+1);            // [N] (cnt -> start)
  uintptr_t ca  = ((uintptr_t)(pos + N) + 7) & ~(uintptr_t)7;
  int2*  cedge  = (int2*)ca;                 // [E] {src, norm}
  int*   bsum   = (int*)(cedge + E);         // [ceil(N/1024)]

  dim3 blk(256);
  int gN  = (N + 255) / 256;
  int gE  = (E + 255) / 256;
  int gL  = (N + 63) / 64;                   // 64 nodes per 256-thread block
  int gG  = (N + 3) / 4;                     // one wave per node
  int gS  = (N + 1023) / 1024;               // scan blocks

  // 1. LSTM + attention + fc (MFMA, round-7 config, t=0 peeled)
  k_lstm<<<gL, blk, 0, stream>>>(node_yx, w_ih, w_hh, b_ih, b_hh,
                                 att_W, fc_W, fc_b, x1, N);
  // 2. CSR build: deg/count -> (scan1 also does dis) -> scan -> fill
  k_deg_init<<<gN, blk, 0, stream>>>(deg, pos, N);
  k_deg_cnt <<<gE, blk, 0, stream>>>(edge_idx, edge_w, deg, pos, E);
  k_scan1   <<<gS, blk, 0, stream>>>(pos, bsum, deg, N);
  k_scan2   <<<1, dim3(64), 0, stream>>>(bsum, gS);
  k_scan3   <<<gS, blk, 0, stream>>>(pos, bsum, rowptr, N);
  k_fill    <<<gE, blk, 0, stream>>>(edge_idx, edge_w, deg, pos, cedge, E);
  // 3. GCN layer 1: x1 -> (xw) -> o1
  k_xw       <<<gN, blk, 0, stream>>>(x1, gcn1_W, gcn1_b, deg, xw, o1, N);
  k_gather<0><<<gG, blk, 0, stream>>>(rowptr, cedge, xw, o1,
                                      nullptr, nullptr, nullptr, nullptr, N);
  // 4. GCN layer 2 + fused final linear: o1 -> (xw, x1 base) -> out
  k_xw       <<<gN, blk, 0, stream>>>(o1, gcn2_W, gcn2_b, deg, xw, x1, N);
  k_gather<1><<<gG, blk, 0, stream>>>(rowptr, cedge, xw, x1,
                                      node_x, lin_W, lin_b, out, N);
}

// Round 11
// 739.670 us; speedup vs baseline: 2.3645x; 1.0835x over previous
//
#include <hip/hip_runtime.h>
#include <hip/hip_bf16.h>
#include <stdint.h>
#include <math.h>

#define H 32
#define LAGN 50
#define LOG2E 1.44269504088896340736f

typedef float f32x4 __attribute__((ext_vector_type(4)));
typedef short bf16x8 __attribute__((ext_vector_type(8)));

__device__ __forceinline__ float rcp_(float x){ return __builtin_amdgcn_rcpf(x); }
__device__ __forceinline__ float ex2_(float x){ return __builtin_amdgcn_exp2f(x); }
// inputs pre-scaled by log2e: sigmoid(g) with g' = g*log2e
__device__ __forceinline__ float sig2_(float gp){ return rcp_(1.0f + ex2_(-gp)); }
// tanh(g) with g' = g*log2e : 1 - 2/(2^(2g') + 1)
__device__ __forceinline__ float th2_(float gp){ return 1.0f - 2.0f*rcp_(ex2_(gp+gp) + 1.0f); }
// tanh of an UNscaled value
__device__ __forceinline__ float th_(float x){ return 1.0f - 2.0f*rcp_(ex2_(x*(2.0f*LOG2E)) + 1.0f); }

// packed f32x2 -> bf16x2 (RNE) via v_cvt_pk path
__device__ __forceinline__ unsigned pk_bf2(float f0, float f1){
  union { __hip_bfloat162 b; unsigned u; } cv;
  cv.b = __float22bfloat162_rn(make_float2(f0, f1));
  return cv.u;
}
// 8 floats (two f32x4) -> hi/lo bf16x8 (error-compensated split)
__device__ __forceinline__ void cvt8v(f32x4 a, f32x4 b, bf16x8& hi, bf16x8& lo){
  union U { bf16x8 v; unsigned d[4]; } Hu, Lu;
  #pragma unroll
  for (int p=0;p<2;p++){
    float f0=a[2*p], f1=a[2*p+1];
    unsigned uh = pk_bf2(f0,f1);
    float h0 = __uint_as_float(uh<<16);
    float h1 = __uint_as_float(uh & 0xffff0000u);
    Hu.d[p] = uh;  Lu.d[p] = pk_bf2(f0-h0, f1-h1);
    float g0=b[2*p], g1=b[2*p+1];
    unsigned ug = pk_bf2(g0,g1);
    float k0 = __uint_as_float(ug<<16);
    float k1 = __uint_as_float(ug & 0xffff0000u);
    Hu.d[2+p] = ug;  Lu.d[2+p] = pk_bf2(g0-k0, g1-k1);
  }
  hi = Hu.v; lo = Lu.v;
}

// ---------------- MFMA LSTM + time-attention + fc (exact r7 body) -----------
// 4 waves x 16 nodes per block, per-wave private LDS slab, no barriers.
// launch_bounds(256,2) = measured sweet spot (116 VGPR, no spill). Weights
// pre-scaled by log2e so gate activations use raw v_exp (exp2) without the
// per-op log2e multiply. NO branch inside the t-loop (r10's peel cost +37us).
__global__ __launch_bounds__(256, 2) void k_lstm(
    const float* __restrict__ yx,    // [N,50]
    const float* __restrict__ w_ih,  // [128]
    const float* __restrict__ w_hh,  // [128,32]
    const float* __restrict__ b_ih,  // [128]
    const float* __restrict__ b_hh,  // [128]
    const float* __restrict__ att_W, // [50,32]
    const float* __restrict__ fc_W,  // [32,32]
    const float* __restrict__ fc_b,  // [32]
    float* __restrict__ x1,          // [N,32] out
    int N)
{
  __shared__ float hs[4][16*36];     // per-wave slab [16 rows][36]
  const int wv = threadIdx.x >> 6;
  const int l  = threadIdx.x & 63;
  const int q  = l >> 4;
  const int cl = l & 15;
  const int nb = blockIdx.x*64 + wv*16;
  float* HS = hs[wv];

  // B fragments of w_hh * log2e (hi/lo bf16), in VGPRs for all 50 steps
  bf16x8 Bhi[8], Blo[8];
  #pragma unroll
  for (int T=0; T<8; ++T){
    const float* p = w_hh + (size_t)(16*T + cl)*H + 8*q;
    f32x4 w0 = *(const f32x4*)p;
    f32x4 w1 = *(const f32x4*)(p+4);
    #pragma unroll
    for (int i=0;i<4;i++){ w0[i] *= LOG2E; w1[i] *= LOG2E; }
    cvt8v(w0, w1, Bhi[T], Blo[T]);
  }

  float wihv[8], bsv[8];
  #pragma unroll
  for (int T=0;T<8;T++){
    int colg = 16*T + cl;
    wihv[T] = w_ih[colg] * LOG2E;
    bsv[T]  = (b_ih[colg] + b_hh[colg]) * LOG2E;
  }

  for (int i=l; i<16*36; i+=64) HS[i] = 0.f;

  float cst[4][2], Sv[4][2], Zv[4];
  #pragma unroll
  for (int idx=0;idx<4;idx++){
    Zv[idx]=0.f; cst[idx][0]=0.f; cst[idx][1]=0.f; Sv[idx][0]=0.f; Sv[idx][1]=0.f;
  }

  const int rr = nb + 4*q;
  const float* yp0 = yx + (size_t)(rr+0<N?rr+0:N-1)*LAGN;
  const float* yp1 = yx + (size_t)(rr+1<N?rr+1:N-1)*LAGN;
  const float* yp2 = yx + (size_t)(rr+2<N?rr+2:N-1)*LAGN;
  const float* yp3 = yx + (size_t)(rr+3<N?rr+3:N-1)*LAGN;

  #pragma unroll 1
  for (int t=0;t<LAGN;t++){
    float xtv[4] = {yp0[t], yp1[t], yp2[t], yp3[t]};
    float at0 = att_W[t*H + cl];
    float at1 = att_W[t*H + cl + 16];

    f32x4 a0 = *(const f32x4*)&HS[36*cl + 8*q];
    f32x4 a1 = *(const f32x4*)&HS[36*cl + 8*q + 4];
    bf16x8 Ahi, Alo;
    cvt8v(a0, a1, Ahi, Alo);

    f32x4 C[8];
    #pragma unroll
    for (int T=0;T<8;T++){
      f32x4 z;
      #pragma unroll
      for (int idx=0;idx<4;idx++) z[idx] = __builtin_fmaf(xtv[idx], wihv[T], bsv[T]);
      z = __builtin_amdgcn_mfma_f32_16x16x32_bf16(Ahi, Blo[T], z, 0,0,0);
      z = __builtin_amdgcn_mfma_f32_16x16x32_bf16(Alo, Bhi[T], z, 0,0,0);
      z = __builtin_amdgcn_mfma_f32_16x16x32_bf16(Ahi, Bhi[T], z, 0,0,0);
      C[T] = z;
    }

    float stp[4], hv[4][2];
    #pragma unroll
    for (int idx=0; idx<4; ++idx){
      stp[idx] = 0.f;
      #pragma unroll
      for (int jh=0; jh<2; ++jh){
        float iv = sig2_(C[jh][idx]);
        float fv = sig2_(C[2+jh][idx]);
        float gv = th2_(C[4+jh][idx]);
        float ov = sig2_(C[6+jh][idx]);
        float cn = fv*cst[idx][jh] + iv*gv;
        cst[idx][jh] = cn;
        float hh = ov*th_(cn);
        hv[idx][jh] = hh;
        stp[idx] += hh * (jh ? at1 : at0);
        HS[36*(4*q+idx) + cl + 16*jh] = hh;
      }
    }

    #pragma unroll
    for (int mask=1; mask<16; mask<<=1){
      #pragma unroll
      for (int idx=0;idx<4;idx++)
        stp[idx] += __shfl_xor(stp[idx], mask);
    }

    #pragma unroll
    for (int idx=0;idx<4;idx++){
      float pex = ex2_(stp[idx]*LOG2E);   // scores bounded -> no max shift
      Zv[idx] += pex;
      Sv[idx][0] += pex*hv[idx][0];
      Sv[idx][1] += pex*hv[idx][1];
    }
  }

  #pragma unroll
  for (int idx=0;idx<4;idx++){
    float iz = rcp_(Zv[idx]);
    HS[36*(4*q+idx) + cl]      = Sv[idx][0]*iz;
    HS[36*(4*q+idx) + cl + 16] = Sv[idx][1]*iz;
  }
  f32x4 p0 = *(const f32x4*)&HS[36*cl + 8*q];
  f32x4 p1 = *(const f32x4*)&HS[36*cl + 8*q + 4];
  bf16x8 Phi, Plo;
  cvt8v(p0, p1, Phi, Plo);

  #pragma unroll
  for (int T=0;T<2;T++){
    f32x4 w0, w1;
    #pragma unroll
    for (int i=0;i<4;i++){
      w0[i] = fc_W[(size_t)(8*q+i)*H + 16*T + cl];
      w1[i] = fc_W[(size_t)(8*q+4+i)*H + 16*T + cl];
    }
    bf16x8 Fhi, Flo;
    cvt8v(w0, w1, Fhi, Flo);
    float fcbv = fc_b[16*T + cl];
    f32x4 z = {fcbv, fcbv, fcbv, fcbv};
    z = __builtin_amdgcn_mfma_f32_16x16x32_bf16(Phi, Flo, z, 0,0,0);
    z = __builtin_amdgcn_mfma_f32_16x16x32_bf16(Plo, Fhi, z, 0,0,0);
    z = __builtin_amdgcn_mfma_f32_16x16x32_bf16(Phi, Fhi, z, 0,0,0);
    #pragma unroll
    for (int idx=0;idx<4;idx++){
      int r = nb + 4*q + idx;
      if (r < N) x1[(size_t)r*H + 16*T + cl] = fmaxf(z[idx], 0.f);
    }
  }
}

// ---------------- GCN: CSR build ---------------------------------------------
__global__ void k_deg_init(float* __restrict__ deg, int* __restrict__ cnt, int N){
  int i = blockIdx.x*blockDim.x + threadIdx.x;
  if (i < N){ deg[i] = 1.0f; cnt[i] = 0; }   // self-loop weight 1.0
}

__global__ void k_deg_cnt(const int* __restrict__ ei, const float* __restrict__ ew,
                          float* __restrict__ deg, int* __restrict__ cnt, int E){
  int e = blockIdx.x*blockDim.x + threadIdx.x;
  if (e < E){
    int d = ei[E+e];
    atomicAdd(&deg[d], ew[e]);
    atomicAdd(&cnt[d], 1);
  }
}

// 3-phase parallel scan; phase 1 also converts deg -> dis = deg^-1/2 in place
__global__ __launch_bounds__(256) void k_scan1(const int* __restrict__ cnt,
                                               int* __restrict__ bsum,
                                               float* __restrict__ deg, int N){
  __shared__ int wsm[4];
  int b = blockIdx.x, t = threadIdx.x;
  int base = b*1024 + t*4;
  int s = 0;
  #pragma unroll
  for (int i=0;i<4;i++) if (base+i < N){
    s += cnt[base+i];
    deg[base+i] = __frcp_rn(sqrtf(deg[base+i]));   // deg >= 1 always
  }
  #pragma unroll
  for (int off=1; off<64; off<<=1) s += __shfl_xor(s, off);
  if ((t&63) == 0) wsm[t>>6] = s;
  __syncthreads();
  if (t == 0) bsum[b] = wsm[0]+wsm[1]+wsm[2]+wsm[3];
}

__global__ __launch_bounds__(64) void k_scan2(int* __restrict__ bsum, int nb){
  int lane = threadIdx.x;
  int carry = 0;
  for (int base=0; base<nb; base+=64){
    int i = base + lane;
    int v = (i<nb) ? bsum[i] : 0;
    int s = v;
    #pragma unroll
    for (int off=1; off<64; off<<=1){ int tt=__shfl_up(s,off); if (lane>=off) s+=tt; }
    if (i<nb) bsum[i] = carry + s - v;
    carry += __shfl(s, 63);
  }
}

__global__ __launch_bounds__(256) void k_scan3(int* cp,       // cnt in, start out
                                               const int* __restrict__ bsum,
                                               int* __restrict__ rowptr, int N){
  __shared__ int wsm[4];
  int b = blockIdx.x, t = threadIdx.x, lane = t&63, w = t>>6;
  int base = b*1024 + t*4;
  int v[4];
  #pragma unroll
  for (int i=0;i<4;i++) v[i] = (base+i<N) ? cp[base+i] : 0;
  int tsum = v[0]+v[1]+v[2]+v[3];
  int s = tsum;
  #pragma unroll
  for (int off=1; off<64; off<<=1){ int tt=__shfl_up(s,off); if (lane>=off) s+=tt; }
  if (lane==63) wsm[w] = s;
  __syncthreads();
  int woff = 0;
  #pragma unroll
  for (int k=0;k<4;k++) if (k<w) woff += wsm[k];
  int e = bsum[b] + woff + (s - tsum);
  #pragma unroll
  for (int i=0;i<4;i++){
    if (base+i < N){ rowptr[base+i] = e; cp[base+i] = e; }
    if (base+i == N-1) rowptr[N] = e + v[i];
    e += v[i];
  }
}

// scatter edges into dst-grouped CSR slots, {src, norm} fused in one int2
__global__ void k_fill(const int* __restrict__ ei, const float* __restrict__ ew,
                       const float* __restrict__ dis, int* __restrict__ pos,
                       int2* __restrict__ cedge, int E){
  int e = blockIdx.x*blockDim.x + threadIdx.x;
  if (e < E){
    int s = ei[e], d = ei[E+e];
    int slot = atomicAdd(&pos[d], 1);
    cedge[slot] = make_int2(s, __float_as_int(dis[s]*ew[e]*dis[d]));
  }
}

// xw = x @ W only (base term now computed inside the gather -> no RMW pass)
__global__ __launch_bounds__(256) void k_xw(
    const float* __restrict__ x, const float* __restrict__ W,
    float* __restrict__ xw, int N)
{
  int n = blockIdx.x*blockDim.x + threadIdx.x;
  if (n >= N) return;
  float xv[H];
  const float4* xr = (const float4*)(x + (size_t)n*H);
  #pragma unroll
  for (int q=0;q<H/4;q++){
    float4 v = xr[q];
    xv[4*q+0]=v.x; xv[4*q+1]=v.y; xv[4*q+2]=v.z; xv[4*q+3]=v.w;
  }
  float* xwr = xw + (size_t)n*H;
  #pragma unroll
  for (int j=0;j<H;j++){
    float a = 0.f;
    #pragma unroll
    for (int k=0;k<H;k++) a += xv[k]*W[k*H+j];
    xwr[j] = a;
  }
}

// atomic-free gather, base fused: one wave per dst node.
// out[n][ch] = (1/deg_n)*xw[n][ch] + b[ch] + sum_e norm*xw[src][ch]  (pure store)
__global__ __launch_bounds__(256) void k_gat1(
    const int* __restrict__ rowptr, const int2* __restrict__ cedge,
    const float* __restrict__ xw, const float* __restrict__ dis,
    const float* __restrict__ b, float* __restrict__ out, int N)
{
  int wid = (int)((blockIdx.x*256u + threadIdx.x) >> 6);
  if (wid >= N) return;
  int lane = threadIdx.x & 63;
  int ch = lane & 31;
  int eh = lane >> 5;
  int start = rowptr[wid], end = rowptr[wid+1];
  float acc = 0.f;
  for (int j = start + eh; j < end; j += 2){
    int2 e = cedge[j];
    acc += __int_as_float(e.y) * xw[(size_t)e.x*H + ch];
  }
  acc += __shfl_xor(acc, 32);
  if (eh == 0){
    float d = dis[wid];
    out[(size_t)wid*H + ch] = d*d*xw[(size_t)wid*H + ch] + b[ch] + acc;
  }
}

// layer-2 gather with base AND final linear fused:
// row = (1/deg)*xw2[n] + b2 + neighbor-sum ; out[n] = relu(row.lw + nx.lw' + lb)
__global__ __launch_bounds__(256) void k_gat2(
    const int* __restrict__ rowptr, const int2* __restrict__ cedge,
    const float* __restrict__ xw, const float* __restrict__ dis,
    const float* __restrict__ b, const float* __restrict__ nx,
    const float* __restrict__ lw, const float* __restrict__ lb,
    float* __restrict__ out, int N)
{
  int wid = (int)((blockIdx.x*256u + threadIdx.x) >> 6);
  if (wid >= N) return;
  int lane = threadIdx.x & 63;
  int ch = lane & 31;
  int eh = lane >> 5;
  int start = rowptr[wid], end = rowptr[wid+1];
  float acc = 0.f;
  for (int j = start + eh; j < end; j += 2){
    int2 e = cedge[j];
    acc += __int_as_float(e.y) * xw[(size_t)e.x*H + ch];
  }
  acc += __shfl_xor(acc, 32);
  float d = dis[wid];
  float v = d*d*xw[(size_t)wid*H + ch] + b[ch] + acc;   // identical in both eh halves
  float s = v * lw[ch];
  #pragma unroll
  for (int mask=1; mask<32; mask<<=1) s += __shfl_xor(s, mask);
  if (lane == 0){
    const float* nr = nx + (size_t)wid*4;
    float a = s + lb[0];
    #pragma unroll
    for (int f=0; f<4; f++) a += nr[f]*lw[H+f];
    out[wid] = fmaxf(a, 0.f);
  }
}

extern "C" void kernel_launch(void* const* d_in, const int* in_sizes, int n_in,
                              void* d_out, int out_size, void* d_ws, size_t ws_size,
                              hipStream_t stream) {
  const float* node_x   = (const float*)d_in[0];
  const float* node_yx  = (const float*)d_in[1];
  const int*   edge_idx = (const int*)  d_in[2];
  const float* edge_w   = (const float*)d_in[3];
  const float* w_ih     = (const float*)d_in[4];
  const float* w_hh     = (const float*)d_in[5];
  const float* b_ih     = (const float*)d_in[6];
  const float* b_hh     = (const float*)d_in[7];
  const float* att_W    = (const float*)d_in[8];
  const float* fc_W     = (const float*)d_in[9];
  const float* fc_b     = (const float*)d_in[10];
  const float* gcn1_W   = (const float*)d_in[11];
  const float* gcn1_b   = (const float*)d_in[12];
  const float* gcn2_W   = (const float*)d_in[13];
  const float* gcn2_b   = (const float*)d_in[14];
  const float* lin_W    = (const float*)d_in[15];
  const float* lin_b    = (const float*)d_in[16];
  float* out = (float*)d_out;

  int N = in_sizes[0] / 4;     // node_x is [N,4]
  int E = in_sizes[3];         // edge_weight is [E]

  float* ws = (float*)d_ws;
  float* x1     = ws;                        // [N*32]
  float* xw     = x1  + (size_t)N*H;         // [N*32]
  float* o1     = xw  + (size_t)N*H;         // [N*32]
  float* deg    = o1  + (size_t)N*H;         // [N] (becomes dis)
  int*   rowptr = (int*)(deg + N);           // [N+1]
  int*   pos    = rowptr + (N+1);            // [N] (cnt -> start)
  uintptr_t ca  = ((uintptr_t)(pos + N) + 7) & ~(uintptr_t)7;
  int2*  cedge  = (int2*)ca;                 // [E] {src, norm}
  int*   bsum   = (int*)(cedge + E);         // [ceil(N/1024)]

  dim3 blk(256);
  int gN  = (N + 255) / 256;
  int gE  = (E + 255) / 256;
  int gL  = (N + 63) / 64;                   // 64 nodes per 256-thread block
  int gG  = (N + 3) / 4;                     // one wave per node
  int gS  = (N + 1023) / 1024;               // scan blocks

  // 1. LSTM + attention + fc (MFMA, r7 body, exp2-domain gates)
  k_lstm<<<gL, blk, 0, stream>>>(node_yx, w_ih, w_hh, b_ih, b_hh,
                                 att_W, fc_W, fc_b, x1, N);
  // 2. CSR build: deg/count -> (scan1 also does dis) -> scan -> fill
  k_deg_init<<<gN, blk, 0, stream>>>(deg, pos, N);
  k_deg_cnt <<<gE, blk, 0, stream>>>(edge_idx, edge_w, deg, pos, E);
  k_scan1   <<<gS, blk, 0, stream>>>(pos, bsum, deg, N);
  k_scan2   <<<1, dim3(64), 0, stream>>>(bsum, gS);
  k_scan3   <<<gS, blk, 0, stream>>>(pos, bsum, rowptr, N);
  k_fill    <<<gE, blk, 0, stream>>>(edge_idx, edge_w, deg, pos, cedge, E);
  // 3. GCN layer 1: x1 -> xw -> o1 (base fused into gather, pure store)
  k_xw  <<<gN, blk, 0, stream>>>(x1, gcn1_W, xw, N);
  k_gat1<<<gG, blk, 0, stream>>>(rowptr, cedge, xw, deg, gcn1_b, o1, N);
  // 4. GCN layer 2 + final linear fused: o1 -> xw -> out
  k_xw  <<<gN, blk, 0, stream>>>(o1, gcn2_W, xw, N);
  k_gat2<<<gG, blk, 0, stream>>>(rowptr, cedge, xw, deg, gcn2_b,
                                 node_x, lin_W, lin_b, out, N);
}